// Round 1
// baseline (123.861 us; speedup 1.0000x reference)
//
#include <hip/hip_runtime.h>

// Problem shapes (fixed by reference setup_inputs):
//   x1: [75, 441, 64] fp32 (query)
//   x2: [1, 5, 5, 441, 64] fp32 -> support = x2[0] reshaped [25, 441, 64]
//   out: [75, 25] fp32
// Math: bar[img][c] = sum_j x[img][j][c] / ||x[img][j][:]||  (norm over C=64)
//       out[i][b]   = dot64(q_bar[i], s_bar[b])

#define N_QUERY   75
#define N_SUPPORT 25
#define N_IMG     (N_QUERY + N_SUPPORT)   // 100
#define HW        441
#define C         64

// Kernel 1: one block per image (100 blocks), 256 threads = 4 waves.
// lane = channel c (C == wavefront size == 64). Each wave handles rows
// j = wave, wave+4, ... For each row: wave-wide sum of squares via
// __shfl_xor (6 steps), then acc += x * rsqrt(ss). LDS-combine the 4 waves.
__global__ __launch_bounds__(256) void normsum_kernel(
    const float* __restrict__ x1,
    const float* __restrict__ x2,
    float* __restrict__ bar /* [N_IMG, C] in workspace */) {

    const int img  = blockIdx.x;            // 0..99
    const int lane = threadIdx.x & 63;      // channel
    const int wave = threadIdx.x >> 6;      // 0..3

    const float* src = (img < N_QUERY)
        ? (x1 + (size_t)img * HW * C)
        : (x2 + (size_t)(img - N_QUERY) * HW * C);

    float acc = 0.f;
    for (int j = wave; j < HW; j += 4) {
        float v = src[j * C + lane];        // coalesced: 64 lanes x 4B contiguous
        float ss = v * v;
        #pragma unroll
        for (int m = 1; m < 64; m <<= 1)
            ss += __shfl_xor(ss, m, 64);
        acc += v * rsqrtf(ss);
    }

    __shared__ float red[4][C];
    red[wave][lane] = acc;
    __syncthreads();
    if (wave == 0) {
        float r = red[0][lane] + red[1][lane] + red[2][lane] + red[3][lane];
        bar[img * C + lane] = r;
    }
}

// Kernel 2: one block (1 wave, 64 threads) per query image. lane = channel.
// For each of the 25 support classes: elementwise product + wave reduction.
__global__ __launch_bounds__(64) void dot_kernel(
    const float* __restrict__ bar,
    float* __restrict__ out /* [N_QUERY, N_SUPPORT] */) {

    const int i    = blockIdx.x;        // 0..74
    const int lane = threadIdx.x;       // 0..63

    const float q = bar[i * C + lane];
    #pragma unroll
    for (int b = 0; b < N_SUPPORT; ++b) {
        float p = q * bar[(N_QUERY + b) * C + lane];
        #pragma unroll
        for (int m = 1; m < 64; m <<= 1)
            p += __shfl_xor(p, m, 64);
        if (lane == 0) out[i * N_SUPPORT + b] = p;
    }
}

extern "C" void kernel_launch(void* const* d_in, const int* in_sizes, int n_in,
                              void* d_out, int out_size, void* d_ws, size_t ws_size,
                              hipStream_t stream) {
    const float* x1 = (const float*)d_in[0];
    const float* x2 = (const float*)d_in[1];   // domain 0 == start of buffer
    float* out = (float*)d_out;
    float* bar = (float*)d_ws;                 // needs N_IMG*C*4 = 25.6 KB

    normsum_kernel<<<N_IMG, 256, 0, stream>>>(x1, x2, bar);
    dot_kernel<<<N_QUERY, 64, 0, stream>>>(bar, out);
}

// Round 2
// 71.768 us; speedup vs baseline: 1.7259x; 1.7259x over previous
//
#include <hip/hip_runtime.h>

// Shapes (fixed):
//   x1: [75, 441, 64] fp32, x2: [1,5,5,441,64] fp32 -> support [25,441,64]
//   out: [75, 25] fp32
// bar[img][c] = sum_j x[img][j][c] * rsqrt(sum_c x[img][j][c]^2)
// out[i][b]   = dot64(q_bar[i], s_bar[b])

#define N_QUERY   75
#define N_SUPPORT 25
#define N_IMG     (N_QUERY + N_SUPPORT)   // 100
#define HW        441
#define C         64
#define NCHUNK    7
#define ROWS      63                      // HW / NCHUNK

// Kernel 1: grid (NCHUNK, N_IMG), block 128 = 2 waves.
// Phase 1: thread t (t < ROWS) owns row j = chunk*ROWS + t:
//   16 independent float4 loads -> sum of squares -> rnorm in LDS.
//   No cross-lane ops, 16-way memory-level parallelism.
// Phase 2: lane = channel c; wave w accumulates rows jj = w, w+2, ...
//   acc += x[row][c] * rnorm_lds[jj]  (LDS read is wave-uniform -> broadcast).
// Combine the 2 waves in LDS, write partial bar[img][chunk][c].
__global__ __launch_bounds__(128) void bar_partial_kernel(
    const float* __restrict__ x1,
    const float* __restrict__ x2,
    float* __restrict__ barp /* [N_IMG, NCHUNK, C] */) {

    const int chunk = blockIdx.x;           // 0..6
    const int img   = blockIdx.y;           // 0..99
    const int tid   = threadIdx.x;          // 0..127
    const int lane  = tid & 63;
    const int wave  = tid >> 6;

    const float* src = (img < N_QUERY)
        ? (x1 + (size_t)img * HW * C)
        : (x2 + (size_t)(img - N_QUERY) * HW * C);
    const float* base = src + (size_t)chunk * ROWS * C;

    __shared__ float rnorm[ROWS];
    __shared__ float red[2][C];

    // ---- Phase 1: per-thread row norm (threads 0..62) ----
    if (tid < ROWS) {
        const float4* p = (const float4*)(base + tid * C);
        float ss = 0.f;
        #pragma unroll 16
        for (int k = 0; k < 16; ++k) {
            float4 v = p[k];
            ss += v.x * v.x + v.y * v.y + v.z * v.z + v.w * v.w;
        }
        rnorm[tid] = rsqrtf(ss);
    }
    __syncthreads();

    // ---- Phase 2: per-channel weighted sum over the chunk's rows ----
    float acc = 0.f;
    #pragma unroll 8
    for (int t = 0; t < 32; ++t) {
        int jj = 2 * t + wave;
        if (jj < ROWS)
            acc += base[jj * C + lane] * rnorm[jj];
    }
    red[wave][lane] = acc;
    __syncthreads();
    if (wave == 0) {
        barp[((size_t)img * NCHUNK + chunk) * C + lane] =
            red[0][lane] + red[1][lane];
    }
}

// Kernel 2: grid 75, block 256 = 4 waves. lane = channel.
// Each wave merges q's 7 partials, then handles b = wave, wave+4, ...:
// merge s_bar partials, elementwise mul, 6-step shuffle reduce, store.
__global__ __launch_bounds__(256) void dot_kernel(
    const float* __restrict__ barp,
    float* __restrict__ out /* [N_QUERY, N_SUPPORT] */) {

    const int i    = blockIdx.x;
    const int lane = threadIdx.x & 63;
    const int wave = threadIdx.x >> 6;

    float q = 0.f;
    #pragma unroll
    for (int k = 0; k < NCHUNK; ++k)
        q += barp[((size_t)i * NCHUNK + k) * C + lane];

    for (int b = wave; b < N_SUPPORT; b += 4) {
        float s = 0.f;
        #pragma unroll
        for (int k = 0; k < NCHUNK; ++k)
            s += barp[((size_t)(N_QUERY + b) * NCHUNK + k) * C + lane];
        float p = q * s;
        #pragma unroll
        for (int m = 1; m < 64; m <<= 1)
            p += __shfl_xor(p, m, 64);
        if (lane == 0) out[i * N_SUPPORT + b] = p;
    }
}

extern "C" void kernel_launch(void* const* d_in, const int* in_sizes, int n_in,
                              void* d_out, int out_size, void* d_ws, size_t ws_size,
                              hipStream_t stream) {
    const float* x1 = (const float*)d_in[0];
    const float* x2 = (const float*)d_in[1];   // domain 0 == start of buffer
    float* out  = (float*)d_out;
    float* barp = (float*)d_ws;                // N_IMG*NCHUNK*C*4 = 179 KB

    dim3 grid1(NCHUNK, N_IMG);
    bar_partial_kernel<<<grid1, 128, 0, stream>>>(x1, x2, barp);
    dot_kernel<<<N_QUERY, 256, 0, stream>>>(barp, out);
}

// Round 3
// 70.948 us; speedup vs baseline: 1.7458x; 1.0116x over previous
//
#include <hip/hip_runtime.h>

// Shapes (fixed):
//   x1: [75, 441, 64] fp32, x2: [1,5,5,441,64] fp32 -> support [25,441,64]
//   out: [75, 25] fp32
// bar[img][c] = sum_j x[img][j][c] * rsqrt(sum_c x[img][j][c]^2)
// out[i][b]   = dot64(q_bar[i], s_bar[b])
//
// Structure: memset(bar,0) -> bar_accum (2100 blocks, atomicAdd into bar)
//            -> dot (75 blocks). Harness overhead (268MB ws poison fill,
//            ~43us) dominates total dur_us; controllable part is ~18us.

#define N_QUERY   75
#define N_SUPPORT 25
#define N_IMG     (N_QUERY + N_SUPPORT)   // 100
#define HW        441
#define C         64
#define NCHUNK    21
#define ROWS      21                      // HW / NCHUNK

// grid (NCHUNK, N_IMG) = 2100 blocks, 128 threads (2 waves) each.
// Phase 1: threads 0..83 each own a quarter-row (4 float4 loads) -> partial
//          sum-of-squares in LDS; threads 0..20 finish rnorm per row.
// Phase 2: lane = channel; each wave accumulates ~10 rows (L1-hot reloads)
//          then atomicAdd into the global bar accumulator (42 adds/address
//          total across the grid -- negligible contention).
__global__ __launch_bounds__(128) void bar_accum_kernel(
    const float* __restrict__ x1,
    const float* __restrict__ x2,
    float* __restrict__ bar /* [N_IMG, C], pre-zeroed */) {

    const int chunk = blockIdx.x;           // 0..20
    const int img   = blockIdx.y;           // 0..99
    const int tid   = threadIdx.x;          // 0..127
    const int lane  = tid & 63;
    const int wave  = tid >> 6;

    const float* src = (img < N_QUERY)
        ? (x1 + (size_t)img * HW * C)
        : (x2 + (size_t)(img - N_QUERY) * HW * C);
    const float* base = src + (size_t)chunk * ROWS * C;

    __shared__ float ssp[ROWS][4];
    __shared__ float rnorm[ROWS];

    // ---- Phase 1: sum of squares, quarter-row per thread ----
    if (tid < ROWS * 4) {
        const int row = tid >> 2;
        const int seg = tid & 3;
        const float4* p = (const float4*)(base + row * C + seg * 16);
        float ss = 0.f;
        #pragma unroll
        for (int k = 0; k < 4; ++k) {
            float4 v = p[k];
            ss += v.x * v.x + v.y * v.y + v.z * v.z + v.w * v.w;
        }
        ssp[row][seg] = ss;
    }
    __syncthreads();
    if (tid < ROWS)
        rnorm[tid] = rsqrtf(ssp[tid][0] + ssp[tid][1] + ssp[tid][2] + ssp[tid][3]);
    __syncthreads();

    // ---- Phase 2: per-channel weighted sum (reloads hit L1) ----
    float acc = 0.f;
    #pragma unroll
    for (int jj = wave; jj < ROWS; jj += 2)
        acc += base[jj * C + lane] * rnorm[jj];

    atomicAdd(&bar[img * C + lane], acc);
}

// 75 blocks x 256 threads (4 waves). lane = channel. bar is tiny (25.6 KB)
// and L2-hot. Each wave handles b = wave, wave+4, ... (7 iterations max).
__global__ __launch_bounds__(256) void dot_kernel(
    const float* __restrict__ bar,
    float* __restrict__ out /* [N_QUERY, N_SUPPORT] */) {

    const int i    = blockIdx.x;
    const int lane = threadIdx.x & 63;
    const int wave = threadIdx.x >> 6;

    const float q = bar[i * C + lane];
    for (int b = wave; b < N_SUPPORT; b += 4) {
        float p = q * bar[(N_QUERY + b) * C + lane];
        #pragma unroll
        for (int m = 1; m < 64; m <<= 1)
            p += __shfl_xor(p, m, 64);
        if (lane == 0) out[i * N_SUPPORT + b] = p;
    }
}

extern "C" void kernel_launch(void* const* d_in, const int* in_sizes, int n_in,
                              void* d_out, int out_size, void* d_ws, size_t ws_size,
                              hipStream_t stream) {
    const float* x1 = (const float*)d_in[0];
    const float* x2 = (const float*)d_in[1];   // domain 0 == start of buffer
    float* out = (float*)d_out;
    float* bar = (float*)d_ws;                 // N_IMG*C*4 = 25.6 KB

    // ws is poisoned 0xAA before every timed launch -> must zero the
    // accumulator each call. Captured as a memset node (async, tiny).
    hipMemsetAsync(bar, 0, (size_t)N_IMG * C * sizeof(float), stream);

    dim3 grid1(NCHUNK, N_IMG);
    bar_accum_kernel<<<grid1, 128, 0, stream>>>(x1, x2, bar);
    dot_kernel<<<N_QUERY, 256, 0, stream>>>(bar, out);
}